// Round 5
// baseline (3154.168 us; speedup 1.0000x reference)
//
#include <hip/hip_runtime.h>
#include <hip/hip_bf16.h>

// Bidirectional GRU encoder, MI355X gfx950.
// Phase 1: prep + one big MFMA GEMM xW = A @ Wcat.
// Phase 2: ONE persistent kernel, 128 blocks x 8 waves. Wave (m,q) owns
//          batch-half m, K-quarter q, all 3 gates (U pinned in regs).
//          NO barrier: h is exchanged as self-validating tagged u32
//          ((bf16)<<16 | step) via sc0/sc1 coherent ops; consumers poll
//          the data until tags match. One __syncthreads per step (xacc).

typedef __attribute__((ext_vector_type(8))) short bf16x8;     // 8 x bf16
typedef __attribute__((ext_vector_type(4))) float f32x4;      // MFMA acc
typedef __attribute__((ext_vector_type(4))) unsigned u32x4;   // 16B tagged h

__device__ __forceinline__ f32x4 mfma_bf16(bf16x8 a, bf16x8 b, f32x4 c) {
  return __builtin_amdgcn_mfma_f32_16x16x32_bf16(a, b, c, 0, 0, 0);
}

__device__ __forceinline__ bf16x8 ld_b128(const __hip_bfloat16* p) {
  bf16x8 r;
  asm volatile("global_load_dwordx4 %0, %1, off" : "=v"(r) : "v"(p));
  return r;
}
__device__ __forceinline__ u32x4 ld_sys_v4(const unsigned* p) {
  u32x4 r;
  asm volatile("global_load_dwordx4 %0, %1, off sc0 sc1" : "=v"(r) : "v"(p));
  return r;
}
__device__ __forceinline__ unsigned ld_u16(const __hip_bfloat16* p) {
  unsigned r;
  asm volatile("global_load_ushort %0, %1, off" : "=v"(r) : "v"(p));
  return r;
}
__device__ __forceinline__ void st_sys_u32(unsigned* p, unsigned v) {
  asm volatile("global_store_dword %0, %1, off sc0 sc1" :: "v"(p), "v"(v) : "memory");
}

__device__ __forceinline__ float bf2f(unsigned u) { return __uint_as_float(u << 16); }

#define WAITV(N) asm volatile("s_waitcnt vmcnt(" #N ")" ::: "memory")

// ---------------- prep kernels ----------------

__global__ __launch_bounds__(256) void transpose_cast(const float* __restrict__ src,
                                                      __hip_bfloat16* __restrict__ dst,
                                                      int R, int C) {
  __shared__ float tile[32][33];
  const int tid = threadIdx.x;
  const int bc = blockIdx.x * 32;
  const int br = blockIdx.y * 32;
#pragma unroll
  for (int i = 0; i < 4; ++i) {
    int idx = tid + i * 256;
    int r = idx >> 5, c = idx & 31;
    tile[r][c] = src[(size_t)(br + r) * C + bc + c];
  }
  __syncthreads();
#pragma unroll
  for (int i = 0; i < 4; ++i) {
    int idx = tid + i * 256;
    int r = idx >> 5, c = idx & 31;
    dst[(size_t)(bc + r) * R + br + c] = __float2bfloat16(tile[c][r]);
  }
}

__global__ __launch_bounds__(256) void gather_embed(const int* __restrict__ x,
                                                    const float* __restrict__ emb,
                                                    __hip_bfloat16* __restrict__ A) {
  int ch = blockIdx.x * 256 + threadIdx.x;
  int row = ch >> 6, seg = ch & 63;
  int b = row & 31, t = row >> 5;
  int idx = x[b * 256 + t];
  const float* s = emb + (size_t)idx * 512 + seg * 8;
  float4 f0 = *(const float4*)(s);
  float4 f1 = *(const float4*)(s + 4);
  __hip_bfloat16 h[8];
  h[0] = __float2bfloat16(f0.x); h[1] = __float2bfloat16(f0.y);
  h[2] = __float2bfloat16(f0.z); h[3] = __float2bfloat16(f0.w);
  h[4] = __float2bfloat16(f1.x); h[5] = __float2bfloat16(f1.y);
  h[6] = __float2bfloat16(f1.z); h[7] = __float2bfloat16(f1.w);
  *(uint4*)(A + (size_t)row * 512 + seg * 8) = *(const uint4*)h;
}

// H layout: [2 bufs][2 dirs][32 rows][1024 cols] u32 tagged.
// buf0 = (h0<<16)|tag0, buf1 = tag 0xFFFF (forces step-1+ waits; kills replay ABA).
__global__ __launch_bounds__(256) void init_h(const float* __restrict__ h0f,
                                              const float* __restrict__ h0b,
                                              unsigned* __restrict__ H) {
  int i = blockIdx.x * 256 + threadIdx.x;   // [0, 65536)
  int d = i >> 15, j = i & 32767;
  float v = d ? h0b[j] : h0f[j];
  unsigned bits = (unsigned)__builtin_bit_cast(unsigned short, __float2bfloat16(v));
  H[i] = (bits << 16);            // tag 0
  H[65536 + i] = 0xFFFFu;         // invalid tag
}

// ---------------- big GEMM: xW[8192][6144] = A[8192][512] @ WT[6144][512]^T ----------------
__global__ __launch_bounds__(256) void gemm_xw(const __hip_bfloat16* __restrict__ A,
                                               const __hip_bfloat16* __restrict__ B,
                                               __hip_bfloat16* __restrict__ C) {
  __shared__ char sm[2 * 128 * 80];
  const int tid = threadIdx.x;
  const int bn = blockIdx.x, bm = blockIdx.y;
  const int l = tid & 63, w = tid >> 6;
  const int wm = w & 1, wn = w >> 1;
  const int lr = l & 15, lk = l >> 4;
  f32x4 acc[4][4] = {};
  for (int k0 = 0; k0 < 512; k0 += 32) {
    __syncthreads();
#pragma unroll
    for (int i = 0; i < 2; ++i) {
      int ch = tid + i * 256;
      int row = ch >> 2, kq = ch & 3;
      uint4 va = *(const uint4*)(A + (size_t)(bm * 128 + row) * 512 + k0 + kq * 8);
      *(uint4*)(sm + row * 80 + kq * 16) = va;
      uint4 vb = *(const uint4*)(B + (size_t)(bn * 128 + row) * 512 + k0 + kq * 8);
      *(uint4*)(sm + 10240 + row * 80 + kq * 16) = vb;
    }
    __syncthreads();
    bf16x8 af[4], bfr[4];
#pragma unroll
    for (int m = 0; m < 4; ++m)
      af[m] = *(const bf16x8*)(sm + (wm * 64 + m * 16 + lr) * 80 + lk * 16);
#pragma unroll
    for (int n = 0; n < 4; ++n)
      bfr[n] = *(const bf16x8*)(sm + 10240 + (wn * 64 + n * 16 + lr) * 80 + lk * 16);
#pragma unroll
    for (int m = 0; m < 4; ++m)
#pragma unroll
      for (int n = 0; n < 4; ++n)
        acc[m][n] = mfma_bf16(af[m], bfr[n], acc[m][n]);
  }
#pragma unroll
  for (int m = 0; m < 4; ++m)
#pragma unroll
    for (int n = 0; n < 4; ++n)
#pragma unroll
      for (int v = 0; v < 4; ++v) {
        int row = bm * 128 + wm * 64 + m * 16 + lk * 4 + v;
        int col = bn * 128 + wn * 64 + n * 16 + lr;
        C[(size_t)row * 6144 + col] = __float2bfloat16(acc[m][n][v]);
      }
}

// ---------------- persistent GRU recurrence (barrier-free, tag-polled) ----------------
// grid = 128 blocks: blockIdx.x = colblk*2 + dir; 512 threads = 8 waves:
// wave w -> (m = w&1, q = w>>1): batch-half m, K-quarter q, ALL 3 gates.
__global__ __launch_bounds__(512, 2) void gru_persist(
    const __hip_bfloat16* __restrict__ xW,
    const __hip_bfloat16* __restrict__ UT,
    const float* __restrict__ bias_f,
    const float* __restrict__ bias_b,
    const float* __restrict__ h0_f,
    const float* __restrict__ h0_b,
    unsigned* H,                // [2][2][32][1024] tagged u32
    float* __restrict__ out) {
  __shared__ float xacc[3][2][3][16][17];   // [q-1][m][g][row][col+pad]

  const int tid = threadIdx.x;
  const int l = tid & 63, w = tid >> 6;
  const int m = w & 1, q = w >> 1;
  const int dir = blockIdx.x & 1;
  const int cb = blockIdx.x >> 1;
  const int c0 = cb * 16;
  const int lr = l & 15, lk = l >> 4;
  const int col = c0 + lr;

  // ---- pin U fragments: gates 0..2, K-slice q*256..+256 ----
  bf16x8 ub[3][8];
  {
#pragma unroll
    for (int g = 0; g < 3; ++g) {
      const __hip_bfloat16* Urow =
          UT + (size_t)(dir * 3072 + g * 1024 + col) * 1024 + q * 256 + lk * 8;
#pragma unroll
      for (int kc = 0; kc < 8; ++kc) ub[g][kc] = ld_b128(Urow + kc * 32);
    }
    WAITV(0);
    __builtin_amdgcn_sched_barrier(0);
  }

  const float* bias = dir ? bias_b : bias_f;
  const float b0z = bias[col],        b0r = bias[1024 + col], b0n = bias[2048 + col];
  const float b1z = bias[3072 + col], b1r = bias[4096 + col], b1n = bias[5120 + col];

  float hp[4];
  {
    const float* h0 = dir ? h0_b : h0_f;
#pragma unroll
    for (int v = 0; v < 4; ++v)
      hp[v] = h0[(m * 16 + lk * 4 + v) * 1024 + col];
  }

  for (int s = 0; s < 256; ++s) {
    const unsigned* hin  = H + (size_t)(s & 1) * 65536 + dir * 32768;
    unsigned*       hout = H + (size_t)((s + 1) & 1) * 65536 + dir * 32768;
    const int t = dir ? (255 - s) : s;

    // ---- issue xW loads first (combiner waves only; drained by retry WAITV) ----
    unsigned xwv[12];
    if (q == 0) {
      const __hip_bfloat16* xp =
          xW + (size_t)(t * 32 + m * 16) * 6144 + dir * 3072 + col;
#pragma unroll
      for (int v = 0; v < 4; ++v)
#pragma unroll
        for (int gg = 0; gg < 3; ++gg)
          xwv[v * 3 + gg] = ld_u16(xp + (size_t)(lk * 4 + v) * 6144 + gg * 1024);
    }

    // ---- tagged h load + validate-retry (the only cross-block sync) ----
    const unsigned* hrow = hin + (size_t)(m * 16 + lr) * 1024 + q * 256 + lk * 8;
    const unsigned tg = (unsigned)s;
    u32x4 t0[8], t1[8];
    for (;;) {
#pragma unroll
      for (int kc = 0; kc < 8; ++kc) {
        t0[kc] = ld_sys_v4(hrow + kc * 32);
        t1[kc] = ld_sys_v4(hrow + kc * 32 + 4);
      }
      WAITV(0);
      __builtin_amdgcn_sched_barrier(0);
      unsigned bad = 0;
#pragma unroll
      for (int kc = 0; kc < 8; ++kc) {
        bad |= (t0[kc][0] ^ tg) | (t0[kc][1] ^ tg) | (t0[kc][2] ^ tg) | (t0[kc][3] ^ tg)
             | (t1[kc][0] ^ tg) | (t1[kc][1] ^ tg) | (t1[kc][2] ^ tg) | (t1[kc][3] ^ tg);
      }
      if (__all((bad & 0xFFFFu) == 0)) break;
    }

    // ---- unpack hi16 pairs -> bf16x8 fragments, then 24 MFMA ----
    f32x4 a0 = {}, a1 = {}, a2 = {};
#pragma unroll
    for (int kc = 0; kc < 8; ++kc) {
      u32x4 pk;
      pk[0] = (t0[kc][0] >> 16) | (t0[kc][1] & 0xFFFF0000u);
      pk[1] = (t0[kc][2] >> 16) | (t0[kc][3] & 0xFFFF0000u);
      pk[2] = (t1[kc][0] >> 16) | (t1[kc][1] & 0xFFFF0000u);
      pk[3] = (t1[kc][2] >> 16) | (t1[kc][3] & 0xFFFF0000u);
      bf16x8 hb = __builtin_bit_cast(bf16x8, pk);
      a0 = mfma_bf16(hb, ub[0][kc], a0);
      a1 = mfma_bf16(hb, ub[1][kc], a1);
      a2 = mfma_bf16(hb, ub[2][kc], a2);
    }

    // ---- partial-sum exchange: q=1..3 write, q=0 combines ----
    if (q) {
#pragma unroll
      for (int v = 0; v < 4; ++v) {
        xacc[q - 1][m][0][lk * 4 + v][lr] = a0[v];
        xacc[q - 1][m][1][lk * 4 + v][lr] = a1[v];
        xacc[q - 1][m][2][lk * 4 + v][lr] = a2[v];
      }
    }
    __syncthreads();
    if (q == 0) {
      float hnv[4];
#pragma unroll
      for (int v = 0; v < 4; ++v) {
        const int row = lk * 4 + v;
        float hUz = a0[v], hUr = a1[v], hUn = a2[v];
#pragma unroll
        for (int qq = 0; qq < 3; ++qq) {
          hUz += xacc[qq][m][0][row][lr];
          hUr += xacc[qq][m][1][row][lr];
          hUn += xacc[qq][m][2][row][lr];
        }
        const float xz = bf2f(xwv[v * 3 + 0] << 16);
        const float xr = bf2f(xwv[v * 3 + 1] << 16);
        const float xn = bf2f(xwv[v * 3 + 2] << 16);
        const float z = 1.f / (1.f + expf(-(bf2f(xwv[v * 3 + 0])  + b0z + hUz + b1z)));
        const float r = 1.f / (1.f + expf(-(bf2f(xwv[v * 3 + 1])  + b0r + hUr + b1r)));
        const float n = tanhf(bf2f(xwv[v * 3 + 2]) + b0n + r * (hUn + b1n));
        const float hn = z * hp[v] + (1.f - z) * n;
        hp[v] = hn;
        hnv[v] = hn;
        (void)xz; (void)xr; (void)xn;
      }
      // critical stores first: tagged h for step s+1
#pragma unroll
      for (int v = 0; v < 4; ++v) {
        const int b = m * 16 + lk * 4 + v;
        const unsigned bits =
            (unsigned)__builtin_bit_cast(unsigned short, __float2bfloat16(hnv[v]));
        st_sys_u32(hout + (size_t)b * 1024 + col, (bits << 16) | (unsigned)(s + 1));
      }
      // lazy stores: f32 outputs
#pragma unroll
      for (int v = 0; v < 4; ++v) {
        const int b = m * 16 + lk * 4 + v;
        out[((size_t)b * 256 + t) * 2048 + dir * 1024 + col] = hnv[v];
        if (s == 255) out[16777216 + dir * 32768 + b * 1024 + col] = hnv[v];
      }
    }
    // no trailing barrier: next step's xacc writes are ordered after this
    // block's tagged stores via the tag-poll data dependency.
  }
}

// ---------------- host ----------------

extern "C" void kernel_launch(void* const* d_in, const int* in_sizes, int n_in,
                              void* d_out, int out_size, void* d_ws, size_t ws_size,
                              hipStream_t stream) {
  const int*   x    = (const int*)d_in[0];
  const float* emb  = (const float*)d_in[1];
  const float* W_f  = (const float*)d_in[2];
  const float* U_f  = (const float*)d_in[3];
  const float* b_f  = (const float*)d_in[4];
  const float* W_b  = (const float*)d_in[5];
  const float* U_b  = (const float*)d_in[6];
  const float* b_b  = (const float*)d_in[7];
  const float* h0_f = (const float*)d_in[8];
  const float* h0_b = (const float*)d_in[9];
  float* out = (float*)d_out;
  char* ws = (char*)d_ws;

  const size_t SZ_A  = (size_t)8192 * 512 * 2;
  const size_t SZ_WT = (size_t)6144 * 512 * 2;
  const size_t SZ_UT = (size_t)6144 * 1024 * 2;
  const size_t SZ_XW = (size_t)8192 * 6144 * 2;

  __hip_bfloat16* A   = (__hip_bfloat16*)(ws);
  __hip_bfloat16* WT  = (__hip_bfloat16*)(ws + SZ_A);
  __hip_bfloat16* UT  = (__hip_bfloat16*)(ws + SZ_A + SZ_WT);
  __hip_bfloat16* XW  = (__hip_bfloat16*)(ws + SZ_A + SZ_WT + SZ_UT);
  unsigned*       H   = (unsigned*)(ws + SZ_A + SZ_WT + SZ_UT + SZ_XW);

  transpose_cast<<<dim3(96, 16), 256, 0, stream>>>(W_f, WT, 512, 3072);
  transpose_cast<<<dim3(96, 16), 256, 0, stream>>>(W_b, WT + (size_t)3072 * 512, 512, 3072);
  transpose_cast<<<dim3(96, 32), 256, 0, stream>>>(U_f, UT, 1024, 3072);
  transpose_cast<<<dim3(96, 32), 256, 0, stream>>>(U_b, UT + (size_t)3072 * 1024, 1024, 3072);
  gather_embed<<<2048, 256, 0, stream>>>(x, emb, A);
  init_h<<<256, 256, 0, stream>>>(h0_f, h0_b, H);

  gemm_xw<<<dim3(48, 64), 256, 0, stream>>>(A, WT, XW);

  void* args[] = {(void*)&XW, (void*)&UT, (void*)&b_f, (void*)&b_b,
                  (void*)&h0_f, (void*)&h0_b, (void*)&H, (void*)&out};
  hipLaunchCooperativeKernel((void*)gru_persist, dim3(128), dim3(512),
                             args, 0, stream);
}

// Round 6
// 2306.759 us; speedup vs baseline: 1.3674x; 1.3674x over previous
//
#include <hip/hip_runtime.h>
#include <hip/hip_bf16.h>

// Bidirectional GRU encoder, MI355X gfx950.
// Phase 1: prep + one big MFMA GEMM xW = A @ Wcat.
// Phase 2: ONE persistent kernel, 128 blocks x 8 waves. Wave (m,q) owns
//          batch-half m, K-quarter q, all 3 gates (U pinned in AGPRs via asm
//          loads). Sync: per-(block,m) flag lines at the coherence point;
//          EVERY wave polls the 128 flags of its direction itself (dwordx2
//          per lane). One __syncthreads per step (xacc exchange only).

typedef __attribute__((ext_vector_type(8))) short bf16x8;     // 8 x bf16
typedef __attribute__((ext_vector_type(4))) float f32x4;      // MFMA acc
typedef __attribute__((ext_vector_type(2))) unsigned u32x2;

__device__ __forceinline__ f32x4 mfma_bf16(bf16x8 a, bf16x8 b, f32x4 c) {
  return __builtin_amdgcn_mfma_f32_16x16x32_bf16(a, b, c, 0, 0, 0);
}

__device__ __forceinline__ bf16x8 ld_b128(const __hip_bfloat16* p) {
  bf16x8 r;
  asm volatile("global_load_dwordx4 %0, %1, off" : "=v"(r) : "v"(p));
  return r;
}
__device__ __forceinline__ bf16x8 ld_sys_b128(const __hip_bfloat16* p) {
  bf16x8 r;
  asm volatile("global_load_dwordx4 %0, %1, off sc0 sc1" : "=v"(r) : "v"(p));
  return r;
}
__device__ __forceinline__ u32x2 ld_sys_v2(const unsigned* p) {
  u32x2 r;
  asm volatile("global_load_dwordx2 %0, %1, off sc0 sc1" : "=v"(r) : "v"(p));
  return r;
}
__device__ __forceinline__ unsigned ld_u16(const __hip_bfloat16* p) {
  unsigned r;
  asm volatile("global_load_ushort %0, %1, off" : "=v"(r) : "v"(p));
  return r;
}
__device__ __forceinline__ void st_sys_u16(__hip_bfloat16* p, unsigned v) {
  asm volatile("global_store_short %0, %1, off sc0 sc1" :: "v"(p), "v"(v) : "memory");
}
__device__ __forceinline__ void st_sys_u32(unsigned* p, unsigned v) {
  asm volatile("global_store_dword %0, %1, off sc0 sc1" :: "v"(p), "v"(v) : "memory");
}

__device__ __forceinline__ float bf2f(unsigned u) { return __uint_as_float(u << 16); }

#define WAITV(N) asm volatile("s_waitcnt vmcnt(" #N ")" ::: "memory")

// ---------------- prep kernels ----------------

__global__ __launch_bounds__(256) void transpose_cast(const float* __restrict__ src,
                                                      __hip_bfloat16* __restrict__ dst,
                                                      int R, int C) {
  __shared__ float tile[32][33];
  const int tid = threadIdx.x;
  const int bc = blockIdx.x * 32;
  const int br = blockIdx.y * 32;
#pragma unroll
  for (int i = 0; i < 4; ++i) {
    int idx = tid + i * 256;
    int r = idx >> 5, c = idx & 31;
    tile[r][c] = src[(size_t)(br + r) * C + bc + c];
  }
  __syncthreads();
#pragma unroll
  for (int i = 0; i < 4; ++i) {
    int idx = tid + i * 256;
    int r = idx >> 5, c = idx & 31;
    dst[(size_t)(bc + r) * R + br + c] = __float2bfloat16(tile[c][r]);
  }
}

__global__ __launch_bounds__(256) void gather_embed(const int* __restrict__ x,
                                                    const float* __restrict__ emb,
                                                    __hip_bfloat16* __restrict__ A) {
  int ch = blockIdx.x * 256 + threadIdx.x;
  int row = ch >> 6, seg = ch & 63;
  int b = row & 31, t = row >> 5;
  int idx = x[b * 256 + t];
  const float* s = emb + (size_t)idx * 512 + seg * 8;
  float4 f0 = *(const float4*)(s);
  float4 f1 = *(const float4*)(s + 4);
  __hip_bfloat16 h[8];
  h[0] = __float2bfloat16(f0.x); h[1] = __float2bfloat16(f0.y);
  h[2] = __float2bfloat16(f0.z); h[3] = __float2bfloat16(f0.w);
  h[4] = __float2bfloat16(f1.x); h[5] = __float2bfloat16(f1.y);
  h[6] = __float2bfloat16(f1.z); h[7] = __float2bfloat16(f1.w);
  *(uint4*)(A + (size_t)row * 512 + seg * 8) = *(const uint4*)h;
}

// H16: [2 bufs][2 dirs][32][1024] bf16; flags: u32[256] = [2 dirs][128]
__global__ __launch_bounds__(256) void init_h(const float* __restrict__ h0f,
                                              const float* __restrict__ h0b,
                                              __hip_bfloat16* __restrict__ h16,
                                              unsigned* __restrict__ flags) {
  int i = blockIdx.x * 256 + threadIdx.x;   // [0, 65536)
  int d = i >> 15, j = i & 32767;
  float v = d ? h0b[j] : h0f[j];
  h16[i] = __float2bfloat16(v);
  if (i < 256) flags[i] = 0u;
}

// ---------------- big GEMM: xW[8192][6144] = A[8192][512] @ WT[6144][512]^T ----------------
__global__ __launch_bounds__(256) void gemm_xw(const __hip_bfloat16* __restrict__ A,
                                               const __hip_bfloat16* __restrict__ B,
                                               __hip_bfloat16* __restrict__ C) {
  __shared__ char sm[2 * 128 * 80];
  const int tid = threadIdx.x;
  const int bn = blockIdx.x, bm = blockIdx.y;
  const int l = tid & 63, w = tid >> 6;
  const int wm = w & 1, wn = w >> 1;
  const int lr = l & 15, lk = l >> 4;
  f32x4 acc[4][4] = {};
  for (int k0 = 0; k0 < 512; k0 += 32) {
    __syncthreads();
#pragma unroll
    for (int i = 0; i < 2; ++i) {
      int ch = tid + i * 256;
      int row = ch >> 2, kq = ch & 3;
      uint4 va = *(const uint4*)(A + (size_t)(bm * 128 + row) * 512 + k0 + kq * 8);
      *(uint4*)(sm + row * 80 + kq * 16) = va;
      uint4 vb = *(const uint4*)(B + (size_t)(bn * 128 + row) * 512 + k0 + kq * 8);
      *(uint4*)(sm + 10240 + row * 80 + kq * 16) = vb;
    }
    __syncthreads();
    bf16x8 af[4], bfr[4];
#pragma unroll
    for (int m = 0; m < 4; ++m)
      af[m] = *(const bf16x8*)(sm + (wm * 64 + m * 16 + lr) * 80 + lk * 16);
#pragma unroll
    for (int n = 0; n < 4; ++n)
      bfr[n] = *(const bf16x8*)(sm + 10240 + (wn * 64 + n * 16 + lr) * 80 + lk * 16);
#pragma unroll
    for (int m = 0; m < 4; ++m)
#pragma unroll
      for (int n = 0; n < 4; ++n)
        acc[m][n] = mfma_bf16(af[m], bfr[n], acc[m][n]);
  }
#pragma unroll
  for (int m = 0; m < 4; ++m)
#pragma unroll
    for (int n = 0; n < 4; ++n)
#pragma unroll
      for (int v = 0; v < 4; ++v) {
        int row = bm * 128 + wm * 64 + m * 16 + lk * 4 + v;
        int col = bn * 128 + wn * 64 + n * 16 + lr;
        C[(size_t)row * 6144 + col] = __float2bfloat16(acc[m][n][v]);
      }
}

// ---------------- persistent GRU recurrence (flag-signaled, all-wave poll) ----------------
// grid = 128 blocks: blockIdx.x = colblk*2 + dir; 512 threads = 8 waves:
// wave w -> (m = w&1, q = w>>1): batch-half m, K-quarter q, ALL 3 gates.
// Protocol: flags[dir*128 + cb*2 + m] == k  <=>  h input for step k is published.
// Combiner wave (q==0,m) stores its 16 rows of h, drains, lane0 sets flag=s+1.
__global__ __launch_bounds__(512, 2) void gru_persist(
    const __hip_bfloat16* __restrict__ xW,
    const __hip_bfloat16* __restrict__ UT,
    const float* __restrict__ bias_f,
    const float* __restrict__ bias_b,
    const float* __restrict__ h0_f,
    const float* __restrict__ h0_b,
    __hip_bfloat16* H16,        // [2 bufs][2 dirs][32][1024]
    unsigned* flags,            // [2 dirs][128]
    float* __restrict__ out) {
  __shared__ float xacc[3][2][3][16][17];   // [q-1][m][g][row][col+pad]

  const int tid = threadIdx.x;
  const int l = tid & 63, w = tid >> 6;
  const int m = w & 1, q = w >> 1;
  const int dir = blockIdx.x & 1;
  const int cb = blockIdx.x >> 1;
  const int c0 = cb * 16;
  const int lr = l & 15, lk = l >> 4;
  const int col = c0 + lr;

  // ---- pin U fragments (land in AGPRs): gates 0..2, K-slice q*256..+256 ----
  bf16x8 ub[3][8];
  {
#pragma unroll
    for (int g = 0; g < 3; ++g) {
      const __hip_bfloat16* Urow =
          UT + (size_t)(dir * 3072 + g * 1024 + col) * 1024 + q * 256 + lk * 8;
#pragma unroll
      for (int kc = 0; kc < 8; ++kc) ub[g][kc] = ld_b128(Urow + kc * 32);
    }
    WAITV(0);
    __builtin_amdgcn_sched_barrier(0);
  }

  const float* bias = dir ? bias_b : bias_f;
  const float b0z = bias[col],        b0r = bias[1024 + col], b0n = bias[2048 + col];
  const float b1z = bias[3072 + col], b1r = bias[4096 + col], b1n = bias[5120 + col];

  float hp[4];
  {
    const float* h0 = dir ? h0_b : h0_f;
#pragma unroll
    for (int v = 0; v < 4; ++v)
      hp[v] = h0[(m * 16 + lk * 4 + v) * 1024 + col];
  }

  const unsigned* flp = flags + dir * 128 + 2 * l;   // this lane's 2 flags

  for (int s = 0; s < 256; ++s) {
    const __hip_bfloat16* hin  = H16 + (size_t)(s & 1) * 65536 + dir * 32768;
    __hip_bfloat16*       hout = H16 + (size_t)((s + 1) & 1) * 65536 + dir * 32768;
    const int t = dir ? (255 - s) : s;

    // ---- issue xW loads first (combiner waves only; retired by poll's WAITV) ----
    unsigned xwv[12];
    if (q == 0) {
      const __hip_bfloat16* xp =
          xW + (size_t)(t * 32 + m * 16) * 6144 + dir * 3072 + col;
#pragma unroll
      for (int v = 0; v < 4; ++v)
#pragma unroll
        for (int gg = 0; gg < 3; ++gg)
          xwv[v * 3 + gg] = ld_u16(xp + (size_t)(lk * 4 + v) * 6144 + gg * 1024);
    }

    // ---- every wave polls all 128 flags of its direction ----
    {
      const unsigned tg = (unsigned)s;
      for (;;) {
        u32x2 f = ld_sys_v2(flp);
        WAITV(0);
        __builtin_amdgcn_sched_barrier(0);
        if (__all(f[0] >= tg && f[1] >= tg)) break;
      }
    }

    // ---- h loads (coherent) + MFMA wait-ladder ----
    const __hip_bfloat16* hrow = hin + (size_t)(m * 16 + lr) * 1024 + q * 256 + lk * 8;
    bf16x8 hb[8];
#pragma unroll
    for (int kc = 0; kc < 8; ++kc) hb[kc] = ld_sys_b128(hrow + kc * 32);

    f32x4 a0 = {}, a1 = {}, a2 = {};
#define KSTEP(kc, n)                                           \
    WAITV(n);                                                  \
    __builtin_amdgcn_sched_barrier(0);                         \
    a0 = mfma_bf16(hb[kc], ub[0][kc], a0);                     \
    a1 = mfma_bf16(hb[kc], ub[1][kc], a1);                     \
    a2 = mfma_bf16(hb[kc], ub[2][kc], a2);
    KSTEP(0, 7) KSTEP(1, 6) KSTEP(2, 5) KSTEP(3, 4)
    KSTEP(4, 3) KSTEP(5, 2) KSTEP(6, 1) KSTEP(7, 0)
#undef KSTEP

    // ---- partial-sum exchange: q=1..3 write, q=0 combines ----
    if (q) {
#pragma unroll
      for (int v = 0; v < 4; ++v) {
        xacc[q - 1][m][0][lk * 4 + v][lr] = a0[v];
        xacc[q - 1][m][1][lk * 4 + v][lr] = a1[v];
        xacc[q - 1][m][2][lk * 4 + v][lr] = a2[v];
      }
    }
    __syncthreads();
    if (q == 0) {
      float hnv[4];
#pragma unroll
      for (int v = 0; v < 4; ++v) {
        const int row = lk * 4 + v;
        float hUz = a0[v], hUr = a1[v], hUn = a2[v];
#pragma unroll
        for (int qq = 0; qq < 3; ++qq) {
          hUz += xacc[qq][m][0][row][lr];
          hUr += xacc[qq][m][1][row][lr];
          hUn += xacc[qq][m][2][row][lr];
        }
        const float z = 1.f / (1.f + expf(-(bf2f(xwv[v * 3 + 0]) + b0z + hUz + b1z)));
        const float r = 1.f / (1.f + expf(-(bf2f(xwv[v * 3 + 1]) + b0r + hUr + b1r)));
        const float n = tanhf(bf2f(xwv[v * 3 + 2]) + b0n + r * (hUn + b1n));
        const float hn = z * hp[v] + (1.f - z) * n;
        hp[v] = hn;
        hnv[v] = hn;
      }
      // critical: publish h for step s+1, drain, then signal
#pragma unroll
      for (int v = 0; v < 4; ++v) {
        const int b = m * 16 + lk * 4 + v;
        st_sys_u16(hout + (size_t)b * 1024 + col,
                   (unsigned)__builtin_bit_cast(unsigned short, __float2bfloat16(hnv[v])));
      }
      WAITV(0);
      if (l == 0) st_sys_u32(flags + dir * 128 + cb * 2 + m, (unsigned)(s + 1));
      // lazy: f32 outputs (off critical path)
#pragma unroll
      for (int v = 0; v < 4; ++v) {
        const int b = m * 16 + lk * 4 + v;
        out[((size_t)b * 256 + t) * 2048 + dir * 1024 + col] = hnv[v];
        if (s == 255) out[16777216 + dir * 32768 + b * 1024 + col] = hnv[v];
      }
    }
  }
}

// ---------------- host ----------------

extern "C" void kernel_launch(void* const* d_in, const int* in_sizes, int n_in,
                              void* d_out, int out_size, void* d_ws, size_t ws_size,
                              hipStream_t stream) {
  const int*   x    = (const int*)d_in[0];
  const float* emb  = (const float*)d_in[1];
  const float* W_f  = (const float*)d_in[2];
  const float* U_f  = (const float*)d_in[3];
  const float* b_f  = (const float*)d_in[4];
  const float* W_b  = (const float*)d_in[5];
  const float* U_b  = (const float*)d_in[6];
  const float* b_b  = (const float*)d_in[7];
  const float* h0_f = (const float*)d_in[8];
  const float* h0_b = (const float*)d_in[9];
  float* out = (float*)d_out;
  char* ws = (char*)d_ws;

  const size_t SZ_A  = (size_t)8192 * 512 * 2;
  const size_t SZ_WT = (size_t)6144 * 512 * 2;
  const size_t SZ_UT = (size_t)6144 * 1024 * 2;
  const size_t SZ_XW = (size_t)8192 * 6144 * 2;
  const size_t SZ_H  = (size_t)2 * 65536 * 2;

  __hip_bfloat16* A   = (__hip_bfloat16*)(ws);
  __hip_bfloat16* WT  = (__hip_bfloat16*)(ws + SZ_A);
  __hip_bfloat16* UT  = (__hip_bfloat16*)(ws + SZ_A + SZ_WT);
  __hip_bfloat16* XW  = (__hip_bfloat16*)(ws + SZ_A + SZ_WT + SZ_UT);
  __hip_bfloat16* H16 = (__hip_bfloat16*)(ws + SZ_A + SZ_WT + SZ_UT + SZ_XW);
  unsigned*       FLG = (unsigned*)(ws + SZ_A + SZ_WT + SZ_UT + SZ_XW + SZ_H);

  transpose_cast<<<dim3(96, 16), 256, 0, stream>>>(W_f, WT, 512, 3072);
  transpose_cast<<<dim3(96, 16), 256, 0, stream>>>(W_b, WT + (size_t)3072 * 512, 512, 3072);
  transpose_cast<<<dim3(96, 32), 256, 0, stream>>>(U_f, UT, 1024, 3072);
  transpose_cast<<<dim3(96, 32), 256, 0, stream>>>(U_b, UT + (size_t)3072 * 1024, 1024, 3072);
  gather_embed<<<2048, 256, 0, stream>>>(x, emb, A);
  init_h<<<256, 256, 0, stream>>>(h0_f, h0_b, H16, FLG);

  gemm_xw<<<dim3(48, 64), 256, 0, stream>>>(A, WT, XW);

  void* args[] = {(void*)&XW, (void*)&UT, (void*)&b_f, (void*)&b_b,
                  (void*)&h0_f, (void*)&h0_b, (void*)&H16, (void*)&FLG, (void*)&out};
  hipLaunchCooperativeKernel((void*)gru_persist, dim3(128), dim3(512),
                             args, 0, stream);
}

// Round 7
// 1759.307 us; speedup vs baseline: 1.7928x; 1.3112x over previous
//
#include <hip/hip_runtime.h>
#include <hip/hip_bf16.h>

// Bidirectional GRU encoder, MI355X gfx950.
// Phase 1: prep + one big MFMA GEMM xW = A @ Wcat.
// Phase 2: ONE persistent kernel, 128 blocks x 8 waves. Wave (m,q) owns
//          batch-half m, K-quarter q, all 3 gates (U pinned via asm loads,
//          lands in unified VGPR/AGPR file). Per-combiner-wave flags; only
//          waves q==3 poll (64 flags each), overlapped with combine.
//          Combiner lanes transposed (lane=row, 4 contig cols) so h publish
//          is a single 8B sc store per lane.

typedef __attribute__((ext_vector_type(8))) short bf16x8;     // 8 x bf16
typedef __attribute__((ext_vector_type(4))) float f32x4;      // MFMA acc
typedef __attribute__((ext_vector_type(2))) unsigned u32x2;

__device__ __forceinline__ f32x4 mfma_bf16(bf16x8 a, bf16x8 b, f32x4 c) {
  return __builtin_amdgcn_mfma_f32_16x16x32_bf16(a, b, c, 0, 0, 0);
}

__device__ __forceinline__ bf16x8 ld_b128(const __hip_bfloat16* p) {
  bf16x8 r;
  asm volatile("global_load_dwordx4 %0, %1, off" : "=v"(r) : "v"(p));
  return r;
}
__device__ __forceinline__ bf16x8 ld_sys_b128(const __hip_bfloat16* p) {
  bf16x8 r;
  asm volatile("global_load_dwordx4 %0, %1, off sc0 sc1" : "=v"(r) : "v"(p));
  return r;
}
__device__ __forceinline__ u32x2 ld_b64(const __hip_bfloat16* p) {
  u32x2 r;
  asm volatile("global_load_dwordx2 %0, %1, off" : "=v"(r) : "v"(p));
  return r;
}
__device__ __forceinline__ unsigned ld_sys_u32(const unsigned* p) {
  unsigned r;
  asm volatile("global_load_dword %0, %1, off sc0 sc1" : "=v"(r) : "v"(p));
  return r;
}
__device__ __forceinline__ void st_sys_u32(unsigned* p, unsigned v) {
  asm volatile("global_store_dword %0, %1, off sc0 sc1" :: "v"(p), "v"(v) : "memory");
}
__device__ __forceinline__ void st_sys_u32x2(__hip_bfloat16* p, u32x2 v) {
  asm volatile("global_store_dwordx2 %0, %1, off sc0 sc1" :: "v"(p), "v"(v) : "memory");
}

// select bf16 half of a packed word as f32
__device__ __forceinline__ float bfsel(unsigned wd, int hi) {
  return __uint_as_float(hi ? (wd & 0xFFFF0000u) : (wd << 16));
}
__device__ __forceinline__ unsigned bfbits(float x) {
  return (unsigned)__builtin_bit_cast(unsigned short, __float2bfloat16(x));
}

#define WAITV(N) asm volatile("s_waitcnt vmcnt(" #N ")" ::: "memory")

// ---------------- prep kernels ----------------

__global__ __launch_bounds__(256) void transpose_cast(const float* __restrict__ src,
                                                      __hip_bfloat16* __restrict__ dst,
                                                      int R, int C) {
  __shared__ float tile[32][33];
  const int tid = threadIdx.x;
  const int bc = blockIdx.x * 32;
  const int br = blockIdx.y * 32;
#pragma unroll
  for (int i = 0; i < 4; ++i) {
    int idx = tid + i * 256;
    int r = idx >> 5, c = idx & 31;
    tile[r][c] = src[(size_t)(br + r) * C + bc + c];
  }
  __syncthreads();
#pragma unroll
  for (int i = 0; i < 4; ++i) {
    int idx = tid + i * 256;
    int r = idx >> 5, c = idx & 31;
    dst[(size_t)(bc + r) * R + br + c] = __float2bfloat16(tile[c][r]);
  }
}

__global__ __launch_bounds__(256) void gather_embed(const int* __restrict__ x,
                                                    const float* __restrict__ emb,
                                                    __hip_bfloat16* __restrict__ A) {
  int ch = blockIdx.x * 256 + threadIdx.x;
  int row = ch >> 6, seg = ch & 63;
  int b = row & 31, t = row >> 5;
  int idx = x[b * 256 + t];
  const float* s = emb + (size_t)idx * 512 + seg * 8;
  float4 f0 = *(const float4*)(s);
  float4 f1 = *(const float4*)(s + 4);
  __hip_bfloat16 h[8];
  h[0] = __float2bfloat16(f0.x); h[1] = __float2bfloat16(f0.y);
  h[2] = __float2bfloat16(f0.z); h[3] = __float2bfloat16(f0.w);
  h[4] = __float2bfloat16(f1.x); h[5] = __float2bfloat16(f1.y);
  h[6] = __float2bfloat16(f1.z); h[7] = __float2bfloat16(f1.w);
  *(uint4*)(A + (size_t)row * 512 + seg * 8) = *(const uint4*)h;
}

// H16: [2 bufs][2 dirs][32][1024] bf16; flags: u32[256] = [2 dirs][64 cb][2 m]
__global__ __launch_bounds__(256) void init_h(const float* __restrict__ h0f,
                                              const float* __restrict__ h0b,
                                              __hip_bfloat16* __restrict__ h16,
                                              unsigned* __restrict__ flags) {
  int i = blockIdx.x * 256 + threadIdx.x;   // [0, 65536)
  int d = i >> 15, j = i & 32767;
  float v = d ? h0b[j] : h0f[j];
  h16[i] = __float2bfloat16(v);
  if (i < 256) flags[i] = 0u;
}

// ---------------- big GEMM: xW[8192][6144] = A[8192][512] @ WT[6144][512]^T ----------------
__global__ __launch_bounds__(256) void gemm_xw(const __hip_bfloat16* __restrict__ A,
                                               const __hip_bfloat16* __restrict__ B,
                                               __hip_bfloat16* __restrict__ C) {
  __shared__ char sm[2 * 128 * 80];
  const int tid = threadIdx.x;
  const int bn = blockIdx.x, bm = blockIdx.y;
  const int l = tid & 63, w = tid >> 6;
  const int wm = w & 1, wn = w >> 1;
  const int lr = l & 15, lk = l >> 4;
  f32x4 acc[4][4] = {};
  for (int k0 = 0; k0 < 512; k0 += 32) {
    __syncthreads();
#pragma unroll
    for (int i = 0; i < 2; ++i) {
      int ch = tid + i * 256;
      int row = ch >> 2, kq = ch & 3;
      uint4 va = *(const uint4*)(A + (size_t)(bm * 128 + row) * 512 + k0 + kq * 8);
      *(uint4*)(sm + row * 80 + kq * 16) = va;
      uint4 vb = *(const uint4*)(B + (size_t)(bn * 128 + row) * 512 + k0 + kq * 8);
      *(uint4*)(sm + 10240 + row * 80 + kq * 16) = vb;
    }
    __syncthreads();
    bf16x8 af[4], bfr[4];
#pragma unroll
    for (int m = 0; m < 4; ++m)
      af[m] = *(const bf16x8*)(sm + (wm * 64 + m * 16 + lr) * 80 + lk * 16);
#pragma unroll
    for (int n = 0; n < 4; ++n)
      bfr[n] = *(const bf16x8*)(sm + 10240 + (wn * 64 + n * 16 + lr) * 80 + lk * 16);
#pragma unroll
    for (int m = 0; m < 4; ++m)
#pragma unroll
      for (int n = 0; n < 4; ++n)
        acc[m][n] = mfma_bf16(af[m], bfr[n], acc[m][n]);
  }
#pragma unroll
  for (int m = 0; m < 4; ++m)
#pragma unroll
    for (int n = 0; n < 4; ++n)
#pragma unroll
      for (int v = 0; v < 4; ++v) {
        int row = bm * 128 + wm * 64 + m * 16 + lk * 4 + v;
        int col = bn * 128 + wn * 64 + n * 16 + lr;
        C[(size_t)row * 6144 + col] = __float2bfloat16(acc[m][n][v]);
      }
}

// ---------------- persistent GRU recurrence ----------------
// grid = 128 blocks: blockIdx.x = colblk*2 + dir; 512 threads = 8 waves:
// wave w -> (m = w&1, q = w>>1): batch-half m, K-quarter q, ALL 3 gates.
// Step: [A-barrier] MFMA phase -> xacc[q] -> [B-barrier] -> {q0: combine+
// publish+flag | q3: poll flags(s+1)} -> next iteration's A-barrier.
__global__ __launch_bounds__(512, 2) void gru_persist(
    const __hip_bfloat16* __restrict__ xW,
    const __hip_bfloat16* __restrict__ UT,
    const float* __restrict__ bias_f,
    const float* __restrict__ bias_b,
    const float* __restrict__ h0_f,
    const float* __restrict__ h0_b,
    __hip_bfloat16* H16,        // [2 bufs][2 dirs][32][1024]
    unsigned* flags,            // [2 dirs][64 cb][2 m]
    float* __restrict__ out) {
  __shared__ float xacc[4][2][3][16][24];   // [q][m][g][row][col+pad]

  const int tid = threadIdx.x;
  const int l = tid & 63, w = tid >> 6;
  const int m = w & 1, q = w >> 1;
  const int dir = blockIdx.x & 1;
  const int cb = blockIdx.x >> 1;
  const int c0 = cb * 16;
  const int lr = l & 15, lk = l >> 4;
  const int col = c0 + lr;          // MFMA-operand column (B-frag row)
  const int cbase = c0 + lk * 4;    // combiner's 4-col base
  const int b = m * 16 + lr;        // combiner's batch row

  // ---- pin U fragments: gates 0..2, K-slice q*256..+256 ----
  bf16x8 ub[3][8];
  {
#pragma unroll
    for (int g = 0; g < 3; ++g) {
      const __hip_bfloat16* Urow =
          UT + (size_t)(dir * 3072 + g * 1024 + col) * 1024 + q * 256 + lk * 8;
#pragma unroll
      for (int kc = 0; kc < 8; ++kc) ub[g][kc] = ld_b128(Urow + kc * 32);
    }
    WAITV(0);
    __builtin_amdgcn_sched_barrier(0);
  }

  // ---- combiner-only loop invariants (harmless for other waves) ----
  const float* bias = dir ? bias_b : bias_f;
  const f32x4 bz0 = *(const f32x4*)&bias[cbase];
  const f32x4 br0 = *(const f32x4*)&bias[1024 + cbase];
  const f32x4 bn0 = *(const f32x4*)&bias[2048 + cbase];
  const f32x4 bz1 = *(const f32x4*)&bias[3072 + cbase];
  const f32x4 br1 = *(const f32x4*)&bias[4096 + cbase];
  const f32x4 bn1 = *(const f32x4*)&bias[5120 + cbase];
  f32x4 hp;
  {
    const float* h0 = dir ? h0_b : h0_f;
    hp = *(const f32x4*)&h0[(size_t)b * 1024 + cbase];
  }

  for (int s = 0; s < 256; ++s) {
    const __hip_bfloat16* hin  = H16 + (size_t)(s & 1) * 65536 + dir * 32768;
    __hip_bfloat16*       hout = H16 + (size_t)((s + 1) & 1) * 65536 + dir * 32768;
    const int t = dir ? (255 - s) : s;

    __syncthreads();   // BARRIER A: h(s) published (pollers confirmed last iter)

    // ---- combiner xW loads (3 x 8B, plain); issued before hb so the
    //      vmcnt ladder constants still mark hb[kc] ready at vmcnt(7-kc).
    u32x2 xw[3];
    if (q == 0) {
      const __hip_bfloat16* xp =
          xW + (size_t)(t * 32 + b) * 6144 + dir * 3072 + cbase;
      xw[0] = ld_b64(xp);
      xw[1] = ld_b64(xp + 1024);
      xw[2] = ld_b64(xp + 2048);
    }

    // ---- h loads (coherent) + MFMA wait-ladder ----
    const __hip_bfloat16* hrow = hin + (size_t)(m * 16 + lr) * 1024 + q * 256 + lk * 8;
    bf16x8 hb[8];
#pragma unroll
    for (int kc = 0; kc < 8; ++kc) hb[kc] = ld_sys_b128(hrow + kc * 32);

    f32x4 a0 = {}, a1 = {}, a2 = {};
#define KSTEP(kc, n)                                           \
    WAITV(n);                                                  \
    __builtin_amdgcn_sched_barrier(0);                         \
    a0 = mfma_bf16(hb[kc], ub[0][kc], a0);                     \
    a1 = mfma_bf16(hb[kc], ub[1][kc], a1);                     \
    a2 = mfma_bf16(hb[kc], ub[2][kc], a2);
    KSTEP(0, 7) KSTEP(1, 6) KSTEP(2, 5) KSTEP(3, 4)
    KSTEP(4, 3) KSTEP(5, 2) KSTEP(6, 1) KSTEP(7, 0)
#undef KSTEP

    // ---- all waves write their partials ----
#pragma unroll
    for (int v = 0; v < 4; ++v) {
      xacc[q][m][0][lk * 4 + v][lr] = a0[v];
      xacc[q][m][1][lk * 4 + v][lr] = a1[v];
      xacc[q][m][2][lk * 4 + v][lr] = a2[v];
    }
    __syncthreads();   // BARRIER B: xacc(s) complete

    if (q == 0) {
      // transposed roles: this lane handles row b = m*16+lr, cols cbase..+3
      f32x4 hz = {}, hr = {}, hn = {};
#pragma unroll
      for (int qq = 0; qq < 4; ++qq) {
        hz += *(const f32x4*)&xacc[qq][m][0][lr][lk * 4];
        hr += *(const f32x4*)&xacc[qq][m][1][lr][lk * 4];
        hn += *(const f32x4*)&xacc[qq][m][2][lr][lk * 4];
      }
      f32x4 hnew;
#pragma unroll
      for (int v = 0; v < 4; ++v) {
        const unsigned wd0 = xw[0][v >> 1], wd1 = xw[1][v >> 1], wd2 = xw[2][v >> 1];
        const int hi = v & 1;
        const float z = 1.f / (1.f + expf(-(bfsel(wd0, hi) + bz0[v] + hz[v] + bz1[v])));
        const float r = 1.f / (1.f + expf(-(bfsel(wd1, hi) + br0[v] + hr[v] + br1[v])));
        const float n = tanhf(bfsel(wd2, hi) + bn0[v] + r * (hn[v] + bn1[v]));
        hnew[v] = z * hp[v] + (1.f - z) * n;
      }
      hp = hnew;
      // publish h(s+1): one 8B coherent store
      u32x2 pk;
      pk[0] = bfbits(hnew[0]) | (bfbits(hnew[1]) << 16);
      pk[1] = bfbits(hnew[2]) | (bfbits(hnew[3]) << 16);
      st_sys_u32x2(hout + (size_t)b * 1024 + cbase, pk);
      WAITV(0);
      if (l == 0 && s < 255)
        st_sys_u32(flags + dir * 128 + cb * 2 + m, (unsigned)(s + 1));
      // off-critical-path outputs (plain stores)
      *(f32x4*)&out[((size_t)b * 256 + t) * 2048 + dir * 1024 + cbase] = hnew;
      if (s == 255)
        *(f32x4*)&out[16777216 + dir * 32768 + (size_t)b * 1024 + cbase] = hnew;
    } else if (q == 3 && s < 255) {
      // poller wave for batch-half m: 64 flags, one per lane
      const unsigned* fp = flags + dir * 128 + l * 2 + m;
      const unsigned tg = (unsigned)(s + 1);
      for (;;) {
        unsigned f = ld_sys_u32(fp);
        WAITV(0);
        __builtin_amdgcn_sched_barrier(0);
        if (__all(f >= tg)) break;
        __builtin_amdgcn_s_sleep(1);
      }
    }
    // next iteration's BARRIER A is the meet point
  }
}

// ---------------- host ----------------

extern "C" void kernel_launch(void* const* d_in, const int* in_sizes, int n_in,
                              void* d_out, int out_size, void* d_ws, size_t ws_size,
                              hipStream_t stream) {
  const int*   x    = (const int*)d_in[0];
  const float* emb  = (const float*)d_in[1];
  const float* W_f  = (const float*)d_in[2];
  const float* U_f  = (const float*)d_in[3];
  const float* b_f  = (const float*)d_in[4];
  const float* W_b  = (const float*)d_in[5];
  const float* U_b  = (const float*)d_in[6];
  const float* b_b  = (const float*)d_in[7];
  const float* h0_f = (const float*)d_in[8];
  const float* h0_b = (const float*)d_in[9];
  float* out = (float*)d_out;
  char* ws = (char*)d_ws;

  const size_t SZ_A  = (size_t)8192 * 512 * 2;
  const size_t SZ_WT = (size_t)6144 * 512 * 2;
  const size_t SZ_UT = (size_t)6144 * 1024 * 2;
  const size_t SZ_XW = (size_t)8192 * 6144 * 2;
  const size_t SZ_H  = (size_t)2 * 65536 * 2;

  __hip_bfloat16* A   = (__hip_bfloat16*)(ws);
  __hip_bfloat16* WT  = (__hip_bfloat16*)(ws + SZ_A);
  __hip_bfloat16* UT  = (__hip_bfloat16*)(ws + SZ_A + SZ_WT);
  __hip_bfloat16* XW  = (__hip_bfloat16*)(ws + SZ_A + SZ_WT + SZ_UT);
  __hip_bfloat16* H16 = (__hip_bfloat16*)(ws + SZ_A + SZ_WT + SZ_UT + SZ_XW);
  unsigned*       FLG = (unsigned*)(ws + SZ_A + SZ_WT + SZ_UT + SZ_XW + SZ_H);

  transpose_cast<<<dim3(96, 16), 256, 0, stream>>>(W_f, WT, 512, 3072);
  transpose_cast<<<dim3(96, 16), 256, 0, stream>>>(W_b, WT + (size_t)3072 * 512, 512, 3072);
  transpose_cast<<<dim3(96, 32), 256, 0, stream>>>(U_f, UT, 1024, 3072);
  transpose_cast<<<dim3(96, 32), 256, 0, stream>>>(U_b, UT + (size_t)3072 * 1024, 1024, 3072);
  gather_embed<<<2048, 256, 0, stream>>>(x, emb, A);
  init_h<<<256, 256, 0, stream>>>(h0_f, h0_b, H16, FLG);

  gemm_xw<<<dim3(48, 64), 256, 0, stream>>>(A, WT, XW);

  void* args[] = {(void*)&XW, (void*)&UT, (void*)&b_f, (void*)&b_b,
                  (void*)&h0_f, (void*)&h0_b, (void*)&H16, (void*)&FLG, (void*)&out};
  hipLaunchCooperativeKernel((void*)gru_persist, dim3(128), dim3(512),
                             args, 0, stream);
}

// Round 9
// 985.818 us; speedup vs baseline: 3.1995x; 1.7846x over previous
//
#include <hip/hip_runtime.h>
#include <hip/hip_bf16.h>

// Bidirectional GRU encoder, MI355X gfx950.
// Phase 1: prep + one big MFMA GEMM xW = A @ Wcat.
// Phase 2: ONE persistent kernel, grid 128 x 512 (proven co-resident).
//   Recurrence is batch-row independent -> 4 worlds = (dir x batch-half),
//   each 16 rows x 1024 cols on 32 blocks (32 cols/block). Device-scope
//   (sc0 sc1) h exchange + per-block flags; wave0 polls its world's 32 flags.
//   No placement assumptions, no registration gates (R8 deadlock lesson).

typedef __attribute__((ext_vector_type(8))) short bf16x8;     // 8 x bf16
typedef __attribute__((ext_vector_type(4))) float f32x4;      // MFMA acc

__device__ __forceinline__ f32x4 mfma_bf16(bf16x8 a, bf16x8 b, f32x4 c) {
  return __builtin_amdgcn_mfma_f32_16x16x32_bf16(a, b, c, 0, 0, 0);
}

// ---- asm memory helpers ----
__device__ __forceinline__ bf16x8 ld_b128(const __hip_bfloat16* p) {       // plain
  bf16x8 r; asm volatile("global_load_dwordx4 %0, %1, off" : "=v"(r) : "v"(p)); return r;
}
__device__ __forceinline__ bf16x8 ld_b128_dev(const unsigned* p) {         // device-coherent
  bf16x8 r; asm volatile("global_load_dwordx4 %0, %1, off sc0 sc1" : "=v"(r) : "v"(p)); return r;
}
__device__ __forceinline__ unsigned ld_u32_pl(const void* p) {
  unsigned r; asm volatile("global_load_dword %0, %1, off" : "=v"(r) : "v"(p)); return r;
}
__device__ __forceinline__ unsigned ld_u32_dev(const unsigned* p) {
  unsigned r; asm volatile("global_load_dword %0, %1, off sc0 sc1" : "=v"(r) : "v"(p)); return r;
}
__device__ __forceinline__ void st_u32_dev(unsigned* p, unsigned v) {
  asm volatile("global_store_dword %0, %1, off sc0 sc1" :: "v"(p), "v"(v) : "memory");
}

__device__ __forceinline__ float bfsel(unsigned wd, int hi) {
  return __uint_as_float(hi ? (wd & 0xFFFF0000u) : (wd << 16));
}
__device__ __forceinline__ unsigned bfbits(float x) {
  return (unsigned)__builtin_bit_cast(unsigned short, __float2bfloat16(x));
}

#define WAITV(N) asm volatile("s_waitcnt vmcnt(" #N ")" ::: "memory")
#define SB0() __builtin_amdgcn_sched_barrier(0)

// ---------------- prep kernels ----------------

__global__ __launch_bounds__(256) void transpose_cast(const float* __restrict__ src,
                                                      __hip_bfloat16* __restrict__ dst,
                                                      int R, int C) {
  __shared__ float tile[32][33];
  const int tid = threadIdx.x;
  const int bc = blockIdx.x * 32;
  const int br = blockIdx.y * 32;
#pragma unroll
  for (int i = 0; i < 4; ++i) {
    int idx = tid + i * 256;
    int r = idx >> 5, c = idx & 31;
    tile[r][c] = src[(size_t)(br + r) * C + bc + c];
  }
  __syncthreads();
#pragma unroll
  for (int i = 0; i < 4; ++i) {
    int idx = tid + i * 256;
    int r = idx >> 5, c = idx & 31;
    dst[(size_t)(bc + r) * R + br + c] = __float2bfloat16(tile[c][r]);
  }
}

__global__ __launch_bounds__(256) void gather_embed(const int* __restrict__ x,
                                                    const float* __restrict__ emb,
                                                    __hip_bfloat16* __restrict__ A) {
  int ch = blockIdx.x * 256 + threadIdx.x;
  int row = ch >> 6, seg = ch & 63;
  int b = row & 31, t = row >> 5;
  int idx = x[b * 256 + t];
  const float* s = emb + (size_t)idx * 512 + seg * 8;
  float4 f0 = *(const float4*)(s);
  float4 f1 = *(const float4*)(s + 4);
  __hip_bfloat16 h[8];
  h[0] = __float2bfloat16(f0.x); h[1] = __float2bfloat16(f0.y);
  h[2] = __float2bfloat16(f0.z); h[3] = __float2bfloat16(f0.w);
  h[4] = __float2bfloat16(f1.x); h[5] = __float2bfloat16(f1.y);
  h[6] = __float2bfloat16(f1.z); h[7] = __float2bfloat16(f1.w);
  *(uint4*)(A + (size_t)row * 512 + seg * 8) = *(const uint4*)h;
}

// H: [4 worlds][2 par][16 rows][512 u32(bf16-pair)]; FLG: [4 worlds][32]*16B-stride
__global__ __launch_bounds__(256) void init_h(const float* __restrict__ h0f,
                                              const float* __restrict__ h0b,
                                              unsigned* __restrict__ H,
                                              unsigned* __restrict__ FLG) {
  int i = blockIdx.x * 256 + threadIdx.x;    // [0, 32768)
  int w = i >> 13, rem = i & 8191;
  int row = rem >> 9, p = rem & 511;
  const float* h0 = (w & 1) ? h0b : h0f;
  int b = (w >> 1) * 16 + row;
  float f0 = h0[b * 1024 + 2 * p];
  float f1 = h0[b * 1024 + 2 * p + 1];
  H[w * 16384 + row * 512 + p] = bfbits(f0) | (bfbits(f1) << 16);
  if (i < 2048) FLG[i] = 0u;
}

// ---------------- big GEMM: xW[8192][6144] = A[8192][512] @ WT[6144][512]^T ----------------
__global__ __launch_bounds__(256) void gemm_xw(const __hip_bfloat16* __restrict__ A,
                                               const __hip_bfloat16* __restrict__ B,
                                               __hip_bfloat16* __restrict__ C) {
  __shared__ char sm[2 * 128 * 80];
  const int tid = threadIdx.x;
  const int bn = blockIdx.x, bm = blockIdx.y;
  const int l = tid & 63, w = tid >> 6;
  const int wm = w & 1, wn = w >> 1;
  const int lr = l & 15, lk = l >> 4;
  f32x4 acc[4][4] = {};
  for (int k0 = 0; k0 < 512; k0 += 32) {
    __syncthreads();
#pragma unroll
    for (int i = 0; i < 2; ++i) {
      int ch = tid + i * 256;
      int row = ch >> 2, kq = ch & 3;
      uint4 va = *(const uint4*)(A + (size_t)(bm * 128 + row) * 512 + k0 + kq * 8);
      *(uint4*)(sm + row * 80 + kq * 16) = va;
      uint4 vb = *(const uint4*)(B + (size_t)(bn * 128 + row) * 512 + k0 + kq * 8);
      *(uint4*)(sm + 10240 + row * 80 + kq * 16) = vb;
    }
    __syncthreads();
    bf16x8 af[4], bfr[4];
#pragma unroll
    for (int m = 0; m < 4; ++m)
      af[m] = *(const bf16x8*)(sm + (wm * 64 + m * 16 + lr) * 80 + lk * 16);
#pragma unroll
    for (int n = 0; n < 4; ++n)
      bfr[n] = *(const bf16x8*)(sm + 10240 + (wn * 64 + n * 16 + lr) * 80 + lk * 16);
#pragma unroll
    for (int m = 0; m < 4; ++m)
#pragma unroll
      for (int n = 0; n < 4; ++n)
        acc[m][n] = mfma_bf16(af[m], bfr[n], acc[m][n]);
  }
#pragma unroll
  for (int m = 0; m < 4; ++m)
#pragma unroll
    for (int n = 0; n < 4; ++n)
#pragma unroll
      for (int v = 0; v < 4; ++v) {
        int row = bm * 128 + wm * 64 + m * 16 + lk * 4 + v;
        int col = bn * 128 + wn * 64 + n * 16 + lr;
        C[(size_t)row * 6144 + col] = __float2bfloat16(acc[m][n][v]);
      }
}

// ---------------- persistent GRU: 4 worlds x 32 blocks ----------------
// grid 128: world w = bi&3 (dir=w&1, batch-half mh=w>>1), rank r = bi>>2.
// Block owns cols r*32..+32, all 16 rows of its world.
// 8 waves = K-split 8 (128 K each): ub[6 tiles][4 kc] pinned (96 VGPRs).
// Step: [xw issue] [wave0: poll 32 flags>=s] [WAITV(0)] [barrier A]
//       [hb dev-loads + 24-MFMA ladder] [xacc] [barrier B]
//       [256 threads: combine + 4B dev publish + drain] [barrier C] [tid0 flag=s+1]
__global__ __launch_bounds__(512, 2) void gru_persist(
    const __hip_bfloat16* __restrict__ xW,
    const __hip_bfloat16* __restrict__ UT,
    const float* __restrict__ bias_f,
    const float* __restrict__ bias_b,
    const float* __restrict__ h0_f,
    const float* __restrict__ h0_b,
    unsigned* H,                // [4][2][16][512] u32
    unsigned* FLG,              // [4][32] stride-16 u32
    float* __restrict__ out) {
  const int bi = blockIdx.x;
  const int w = bi & 3;
  const int r = bi >> 2;
  const int dir = w & 1, mh = w >> 1;
  const int tid = threadIdx.x;
  const int l = tid & 63, q = tid >> 6;
  const int lr = l & 15, lk = l >> 4;
  const int c0 = r * 32;

  __shared__ float xacc[8][6][16][20];   // [q][tile][row][col+pad]

  // ---- pin U: 6 tiles (g,ch), K-slice q*128 ----
  bf16x8 ub[6][4];
#pragma unroll
  for (int g = 0; g < 3; ++g)
#pragma unroll
    for (int ch = 0; ch < 2; ++ch) {
      const __hip_bfloat16* Urow =
          UT + (size_t)(dir * 3072 + g * 1024 + c0 + ch * 16 + lr) * 1024 + q * 128 + lk * 8;
#pragma unroll
      for (int kc = 0; kc < 4; ++kc)
        ub[g * 2 + ch][kc] = ld_b128(Urow + kc * 32);
    }
  WAITV(0);
  SB0();

  // ---- combiner-thread invariants (tid<256): 1 row x 2 cols ----
  const int crow = tid & 15;            // batch row within world
  const int cp = tid >> 4;              // col-pair 0..15 (tid<256)
  const int cb = mh * 16 + crow;        // global batch row
  const int cg = c0 + 2 * cp;           // global h col (even)
  float2 bz0, br0, bn0, bz1, br1, bn1, hp;
  if (tid < 256) {
    const float* bias = dir ? bias_b : bias_f;
    bz0 = *(const float2*)&bias[cg];
    br0 = *(const float2*)&bias[1024 + cg];
    bn0 = *(const float2*)&bias[2048 + cg];
    bz1 = *(const float2*)&bias[3072 + cg];
    br1 = *(const float2*)&bias[4096 + cg];
    bn1 = *(const float2*)&bias[5120 + cg];
    const float* h0 = dir ? h0_b : h0_f;
    hp = *(const float2*)&h0[(size_t)cb * 1024 + cg];
  }

  unsigned* Hw  = H + w * 16384;
  unsigned* FLw = FLG + w * 512;
  const unsigned* flp = FLw + (l & 31) * 16;   // wave0's poll targets

  for (int s = 0; s < 256; ++s) {
    const int par = s & 1;
    const int t = dir ? (255 - s) : s;

    // ---- xW loads (combiner threads; values needed only at combine) ----
    unsigned xwz = 0, xwr = 0, xwn = 0;
    if (q < 4) {
      const __hip_bfloat16* xp = xW + (size_t)(t * 32 + cb) * 6144 + dir * 3072 + cg;
      xwz = ld_u32_pl(xp);
      xwr = ld_u32_pl(xp + 1024);
      xwn = ld_u32_pl(xp + 2048);
    }

    // ---- wave0 polls world's 32 flags >= s (h(s) fully published) ----
    if (q == 0) {
      const unsigned tg = (unsigned)s;
      for (;;) {
        unsigned f = ld_u32_dev(flp);
        WAITV(0);
        SB0();
        if (__all(f >= tg)) break;
      }
    }
    WAITV(0);          // non-pollers: drain xw so everyone has 0 outstanding
    __syncthreads();   // BARRIER A: h(s) readable

    // ---- h loads (device-coherent) + MFMA ladder ----
    const unsigned* hrow = Hw + par * 8192 + lr * 512 + q * 64 + lk * 4;
    bf16x8 hb[4];
#pragma unroll
    for (int kc = 0; kc < 4; ++kc)
      hb[kc] = ld_b128_dev(hrow + kc * 16);

    f32x4 acc[6] = {};
#define KSTEP(kc, n)                                                     \
    WAITV(n); SB0();                                                     \
    acc[0] = mfma_bf16(hb[kc], ub[0][kc], acc[0]);                       \
    acc[1] = mfma_bf16(hb[kc], ub[1][kc], acc[1]);                       \
    acc[2] = mfma_bf16(hb[kc], ub[2][kc], acc[2]);                       \
    acc[3] = mfma_bf16(hb[kc], ub[3][kc], acc[3]);                       \
    acc[4] = mfma_bf16(hb[kc], ub[4][kc], acc[4]);                       \
    acc[5] = mfma_bf16(hb[kc], ub[5][kc], acc[5]);
    KSTEP(0, 3) KSTEP(1, 2) KSTEP(2, 1) KSTEP(3, 0)
#undef KSTEP

#pragma unroll
    for (int tile = 0; tile < 6; ++tile)
#pragma unroll
      for (int v = 0; v < 4; ++v)
        xacc[q][tile][lk * 4 + v][lr] = acc[tile][v];
    __syncthreads();   // BARRIER B: partials complete

    if (tid < 256) {
      const int ch = cp >> 3;                 // 16-col tile half
      const int co = (2 * cp) & 15;           // even col offset in tile
      float2 hz = {0.f, 0.f}, hr = {0.f, 0.f}, hn = {0.f, 0.f};
#pragma unroll
      for (int qq = 0; qq < 8; ++qq) {
        float2 a  = *(const float2*)&xacc[qq][ch][crow][co];
        float2 bq = *(const float2*)&xacc[qq][2 + ch][crow][co];
        float2 c  = *(const float2*)&xacc[qq][4 + ch][crow][co];
        hz.x += a.x;  hz.y += a.y;
        hr.x += bq.x; hr.y += bq.y;
        hn.x += c.x;  hn.y += c.y;
      }
      float hnew[2];
#pragma unroll
      for (int j = 0; j < 2; ++j) {
        const float hzj = j ? hz.y : hz.x, hrj = j ? hr.y : hr.x, hnj = j ? hn.y : hn.x;
        const float bz0j = j ? bz0.y : bz0.x, br0j = j ? br0.y : br0.x, bn0j = j ? bn0.y : bn0.x;
        const float bz1j = j ? bz1.y : bz1.x, br1j = j ? br1.y : br1.x, bn1j = j ? bn1.y : bn1.x;
        const float hpj = j ? hp.y : hp.x;
        const float z  = 1.f / (1.f + expf(-(bfsel(xwz, j) + bz0j + hzj + bz1j)));
        const float rr = 1.f / (1.f + expf(-(bfsel(xwr, j) + br0j + hrj + br1j)));
        const float n  = tanhf(bfsel(xwn, j) + bn0j + rr * (hnj + bn1j));
        hnew[j] = z * hpj + (1.f - z) * n;
      }
      hp.x = hnew[0]; hp.y = hnew[1];
      // critical publish: one 4B device store, then drain
      unsigned pk = bfbits(hnew[0]) | (bfbits(hnew[1]) << 16);
      st_u32_dev(Hw + (par ^ 1) * 8192 + crow * 512 + c0 / 2 + cp, pk);
      WAITV(0);
      // off-critical-path outputs (plain)
      *(float2*)&out[((size_t)cb * 256 + t) * 2048 + dir * 1024 + cg] = *(float2*)hnew;
      if (s == 255)
        *(float2*)&out[16777216 + dir * 32768 + (size_t)cb * 1024 + cg] = *(float2*)hnew;
    }
    __syncthreads();   // BARRIER C: all publishes at coherence point
    if (tid == 0) st_u32_dev(FLw + r * 16, (unsigned)(s + 1));
  }
}

// ---------------- host ----------------

extern "C" void kernel_launch(void* const* d_in, const int* in_sizes, int n_in,
                              void* d_out, int out_size, void* d_ws, size_t ws_size,
                              hipStream_t stream) {
  const int*   x    = (const int*)d_in[0];
  const float* emb  = (const float*)d_in[1];
  const float* W_f  = (const float*)d_in[2];
  const float* U_f  = (const float*)d_in[3];
  const float* b_f  = (const float*)d_in[4];
  const float* W_b  = (const float*)d_in[5];
  const float* U_b  = (const float*)d_in[6];
  const float* b_b  = (const float*)d_in[7];
  const float* h0_f = (const float*)d_in[8];
  const float* h0_b = (const float*)d_in[9];
  float* out = (float*)d_out;
  char* ws = (char*)d_ws;

  const size_t SZ_A  = (size_t)8192 * 512 * 2;
  const size_t SZ_WT = (size_t)6144 * 512 * 2;
  const size_t SZ_UT = (size_t)6144 * 1024 * 2;
  const size_t SZ_XW = (size_t)8192 * 6144 * 2;
  const size_t SZ_H  = (size_t)4 * 16384 * 4;

  __hip_bfloat16* A   = (__hip_bfloat16*)(ws);
  __hip_bfloat16* WT  = (__hip_bfloat16*)(ws + SZ_A);
  __hip_bfloat16* UT  = (__hip_bfloat16*)(ws + SZ_A + SZ_WT);
  __hip_bfloat16* XW  = (__hip_bfloat16*)(ws + SZ_A + SZ_WT + SZ_UT);
  unsigned*       H   = (unsigned*)(ws + SZ_A + SZ_WT + SZ_UT + SZ_XW);
  unsigned*       FLG = (unsigned*)(ws + SZ_A + SZ_WT + SZ_UT + SZ_XW + SZ_H);

  transpose_cast<<<dim3(96, 16), 256, 0, stream>>>(W_f, WT, 512, 3072);
  transpose_cast<<<dim3(96, 16), 256, 0, stream>>>(W_b, WT + (size_t)3072 * 512, 512, 3072);
  transpose_cast<<<dim3(96, 32), 256, 0, stream>>>(U_f, UT, 1024, 3072);
  transpose_cast<<<dim3(96, 32), 256, 0, stream>>>(U_b, UT + (size_t)3072 * 1024, 1024, 3072);
  gather_embed<<<2048, 256, 0, stream>>>(x, emb, A);
  init_h<<<128, 256, 0, stream>>>(h0_f, h0_b, H, FLG);

  gemm_xw<<<dim3(48, 64), 256, 0, stream>>>(A, WT, XW);

  void* args[] = {(void*)&XW, (void*)&UT, (void*)&b_f, (void*)&b_b,
                  (void*)&h0_f, (void*)&h0_b, (void*)&H, (void*)&FLG, (void*)&out};
  hipLaunchCooperativeKernel((void*)gru_persist, dim3(128), dim3(512),
                             args, 0, stream);
}